// Round 8
// baseline (526.145 us; speedup 1.0000x reference)
//
#include <hip/hip_runtime.h>
#include <hip/hip_cooperative_groups.h>
#include <math.h>

namespace cg = cooperative_groups;

typedef unsigned long long u64;
typedef unsigned int u32;

#define M_CAND 6960
#define MW 112        // mask row stride in u64 words
#define NW 109

// ws layout (bytes)
#define OFF_BOX   0u          // float4 [2][6960]
#define OFF_SBOX  222720u     // float4 [2][6960]
#define OFF_CS    445440u     // float [2][6960] cand_score
#define OFF_CP    501120u     // u32   [2][6960] cand_pos
#define OFF_SS    556800u     // float [2][6960] sorted scores
#define OFF_KEY   612480u     // u64   [2][6960] full keys
#define OFF_VK    723840u     // u64   [2][6960] valid-compacted keys per level
#define OFF_VC    835200u     // int   [2][8]
#define OFF_CM    835264u     // int   [2][6960] comp indices
#define OFF_MASK  890944u     // u64   [2][6960][112]  (12.47 MB)
// selection scratch ALIASES the mask region (dead before mask stage writes):
#define OFF_GH    OFF_MASK              // u32 [2][16][2048] per-chunk histograms
#define OFF_GC    (OFF_MASK + 262144u)  // u32 [2][18] per-chunk select counts
#define OFF_GL    (OFF_MASK + 262400u)  // u64 [2][18][4096] per-chunk selected lists

__device__ __forceinline__ u32 fmono(float f) {
  u32 u = __float_as_uint(f);
  return (u & 0x80000000u) ? ~u : (u | 0x80000000u);
}
__device__ __forceinline__ float fmono_inv(u32 m) {
  u32 u = (m & 0x80000000u) ? (m & 0x7FFFFFFFu) : ~m;
  return __uint_as_float(u);
}
__device__ __forceinline__ u64 readlane64(u64 v, int l) {
  u32 lo = (u32)__builtin_amdgcn_readlane((int)(u32)v, l);
  u32 hi = (u32)__builtin_amdgcn_readlane((int)(u32)(v >> 32), l);
  return ((u64)hi << 32) | lo;
}
__device__ __forceinline__ u64 shfl_xor64(u64 v, int m) {
  u32 lo = (u32)__shfl_xor((int)(u32)v, m, 64);
  u32 hi = (u32)__shfl_xor((int)(u32)(v >> 32), m, 64);
  return ((u64)hi << 32) | lo;
}

__device__ const int d_dims[5]    = {128, 64, 32, 16, 8};
__device__ const int d_strides[5] = {8, 16, 32, 64, 128};
__device__ const int d_kvals[5]   = {2000, 2000, 2000, 768, 192};
__device__ const int d_segoff[5]  = {0, 2000, 4000, 6000, 6768};
__device__ const int d_logHW[5]   = {14, 12, 10, 8, 6};
// hist: 16 chunk-tasks per image (levels 0-2 only)
__device__ const int d_hlvl[16]   = {0,0,0,0,0,0,0,0,0,0,0,0, 1,1,1, 2};
__device__ const int d_hchk[16]   = {0,1,2,3,4,5,6,7,8,9,10,11, 0,1,2, 0};
__device__ const int d_hbase[3]   = {0, 12, 15};
__device__ const int d_hnum[3]    = {12, 3, 1};
// select: 18 chunk-tasks per image (all levels)
__device__ const int d_slvl[18]   = {0,0,0,0,0,0,0,0,0,0,0,0, 1,1,1, 2, 3, 4};
__device__ const int d_schk[18]   = {0,1,2,3,4,5,6,7,8,9,10,11, 0,1,2, 0, 0, 0};
__device__ const int d_sbase[5]   = {0, 12, 15, 16, 17};
__device__ const int d_snum[5]    = {12, 3, 1, 1, 1};

__device__ __forceinline__ float sigm(float x) { return 1.0f / (1.0f + expf(-x)); }
__device__ __forceinline__ int binof(float s) {
  int b = (int)(s * 2048.0f);
  return b > 2047 ? 2047 : b;
}

struct KArgs {
  const float* cls[5]; const float* reg[5]; const int* ih; const int* iw;
  float4* boxes; float4* sboxes; float* cscore; u32* cpos; float* sscore;
  u64* fkey; u64* vkeys; int* vcnt; int* comp;
  u32* ghist; u32* gcnt; u64* glist; u64* maskp; float* out;
};

__global__ __launch_bounds__(256) void k_mega(KArgs A) {
#pragma clang fp contract(off)
  cg::grid_group grid = cg::this_grid();
  const int blk = blockIdx.x, tid = threadIdx.x;
  __shared__ __align__(16) char SM[41024];
  __shared__ int s_T, s_cnt, s_vb, wvt[4];
  __shared__ int g_tot, g_stop, g_nk[2];

  // ================= stage Z: per-chunk histograms (blocks 0-31) + zero d_out =================
  if (blk < 32) {
    const int img = blk >> 4, bb = blk & 15;
    const int lvl = d_hlvl[bb], c0 = d_hchk[bb] << 12;
    const int n = 3 << d_logHW[lvl];
    const float* cls = A.cls[lvl] + (size_t)img * n;
    u32* hist = (u32*)SM;
    for (int b = tid; b < 2048; b += 256) hist[b] = 0;
    __syncthreads();
    const int end = (c0 + 4096 < n) ? c0 + 4096 : n;
    int e = c0 + tid;
    for (; e + 768 < end; e += 1024) {
      float x0 = cls[e], x1 = cls[e + 256], x2 = cls[e + 512], x3 = cls[e + 768];
      atomicAdd(&hist[binof(sigm(x0))], 1u);
      atomicAdd(&hist[binof(sigm(x1))], 1u);
      atomicAdd(&hist[binof(sigm(x2))], 1u);
      atomicAdd(&hist[binof(sigm(x3))], 1u);
    }
    for (; e < end; e += 256) atomicAdd(&hist[binof(sigm(cls[e]))], 1u);
    __syncthreads();
    u32* outh = A.ghist + ((size_t)img * 16 + bb) * 2048;
    for (int b = tid; b < 2048; b += 256) outh[b] = hist[b];
  } else {
    int zi = (blk - 32) * 256 + tid;
    if (zi < 14000) A.out[zi] = 0.0f;
  }
  grid.sync();

  // ================= stage S2: threshold + select (blocks 0-35) =================
  if (blk < 36) {
    const int img = blk / 18, bb = blk % 18;
    const int lvl = d_slvl[bb], c0 = d_schk[bb] << 12;
    const int lhw = d_logHW[lvl];
    const int HW = 1 << lhw, n = 3 * HW;
    const float* cls = A.cls[lvl] + (size_t)img * n;
    const int k = d_kvals[lvl];
    u32* shist = (u32*)SM;
    u64* sel = (u64*)(SM + 8192);
    if (lvl <= 2) {
      const int hb = d_hbase[lvl], hn = d_hnum[lvl];
      const u32* gh = A.ghist + ((size_t)img * 16 + hb) * 2048;
      for (int b = tid; b < 2048; b += 256) {
        u32 acc = 0;
        for (int c = 0; c < hn; ++c) acc += gh[(size_t)c * 2048 + b];
        shist[b] = acc;
      }
      __syncthreads();
      if (tid < 64) {
        u32 part = 0;
        for (int j = 0; j < 32; ++j) part += shist[tid * 32 + ((j + tid) & 31)];
        u32 ss = part;
        for (int d = 1; d < 64; d <<= 1) {
          u32 o = __shfl_down(ss, d);
          if (tid + d < 64) ss += o;
        }
        u64 m = __ballot(ss >= (u32)k);
        int SB = 63 - __clzll(m);
        if (tid == SB) {
          u32 acc = ss - part;
          int T = SB * 32;
          for (int b = SB * 32 + 31; b >= SB * 32; --b) {
            acc += shist[b];
            if (acc >= (u32)k) { T = b; break; }
          }
          s_T = T;
        }
      }
    } else if (tid == 0) s_T = 0;
    if (tid == 0) s_cnt = 0;
    __syncthreads();
    const int T = s_T;
    const int end = (c0 + 4096 < n) ? c0 + 4096 : n;
    int e = c0 + tid;
    for (; e + 768 < end; e += 1024) {
      float x0 = cls[e], x1 = cls[e + 256], x2 = cls[e + 512], x3 = cls[e + 768];
      float svals[4] = {sigm(x0), sigm(x1), sigm(x2), sigm(x3)};
      int ee[4] = {e, e + 256, e + 512, e + 768};
      for (int q2 = 0; q2 < 4; ++q2) {
        float s = svals[q2];
        if (binof(s) >= T) {
          int eq = ee[q2];
          int a = eq >> lhw, hw = eq & (HW - 1);
          u32 it = (u32)(hw * 3 + a);
          int p = atomicAdd(&s_cnt, 1);
          sel[p] = ((u64)fmono(s) << 32) | (u32)(~it);
        }
      }
    }
    for (; e < end; e += 256) {
      float s = sigm(cls[e]);
      if (binof(s) >= T) {
        int a = e >> lhw, hw = e & (HW - 1);
        u32 it = (u32)(hw * 3 + a);
        int p = atomicAdd(&s_cnt, 1);
        sel[p] = ((u64)fmono(s) << 32) | (u32)(~it);
      }
    }
    __syncthreads();
    int cnt = s_cnt;
    if (tid == 0) A.gcnt[img * 18 + bb] = (u32)cnt;
    u64* gl = A.glist + ((size_t)img * 18 + bb) * 4096;
    for (int p = tid; p < cnt; p += 256) gl[p] = sel[p];
  }
  grid.sync();

  // ================= stage S3: within-level rank -> sorted top-k (blocks 0-159) =================
  if (blk < 160) {
    const int slice = blk & 15;
    const int lvl = (blk >> 4) % 5;
    const int img = blk / 80;
    const int cb = d_sbase[lvl], nc = d_snum[lvl];
    u64* sh = (u64*)SM;   // 32 KB
    int cnts[12];
    int tot = 0;
    for (int c = 0; c < nc; ++c) { cnts[c] = (int)A.gcnt[img * 18 + cb + c]; tot += cnts[c]; }
    if (tot > 4096) tot = 4096;
    const int c0 = slice << 8;
    if (c0 < tot) {
      // flat cooperative staging across chunk lists (independent loads)
      for (int j = tid; j < tot; j += 256) {
        int c = 0, base = 0;
        while (j >= base + cnts[c]) { base += cnts[c]; ++c; }
        sh[j] = A.glist[((size_t)img * 18 + cb + c) * 4096 + (j - base)];
      }
      if (tid == 0 && (tot & 1)) sh[tot] = 0ull;
      __syncthreads();
      const int p = c0 + tid;
      if (p < tot) {
        const u64 mk = sh[p];
        const int cntr = (tot + 1) & ~1;
        int r = 0;
        for (int j = 0; j < cntr; j += 2) {
          ulonglong2 kk = *(const ulonglong2*)&sh[j];
          r += (int)(kk.x > mk) + (int)(kk.y > mk);
        }
        const int k = d_kvals[lvl], off = d_segoff[lvl];
        if (r < k) {
          u32 it = ~(u32)mk;
          A.cscore[img * M_CAND + off + r] = fmono_inv((u32)(mk >> 32));
          A.cpos[img * M_CAND + off + r] = ((u32)lvl << 20) | (it & 0xFFFFFu);
        }
      }
    }
  }
  grid.sync();

  // ================= stage S4: decode boxes + keys (grid-stride) =================
  {
    int t = blk * 256 + tid;
    if (t < 2 * M_CAND) {
      int img = t / M_CAND, slot = t - img * M_CAND;
      float s = A.cscore[t];
      u32 pc = A.cpos[t];
      int lvl = (int)(pc >> 20), idx = (int)(pc & 0xFFFFFu);
      int W = d_dims[lvl], HW = W * W, stride = d_strides[lvl];
      int a = idx % 3, cell = idx / 3;
      int wx = cell % W, hy = cell / W;
      const float rr[3] = {0.5f, 1.0f, 2.0f};
      float sw = (float)(stride * 8);
      float wsz = sw * sqrtf(1.0f / rr[a]);
      float hsz = sw * sqrtf(rr[a]);
      float ax = (float)(wx * stride), ay = (float)(hy * stride);
      float a0 = ax + (-(wsz * 0.5f));
      float a1 = ay + (-(hsz * 0.5f));
      float a2 = ax + (wsz * 0.5f);
      float a3 = ay + (hsz * 0.5f);
      const float* rg = A.reg[lvl] + ((size_t)img * 12 + (size_t)(a * 4)) * HW + (size_t)hy * W + wx;
      float dx = rg[0], dy = rg[HW], dw = rg[2 * HW], dh = rg[3 * HW];
      const float MR = 4.135166556742356f;
      dw = fminf(fmaxf(dw, -MR), MR);
      dh = fminf(fmaxf(dh, -MR), MR);
      float px = (a0 + a2) * 0.5f, py = (a1 + a3) * 0.5f;
      float pw = a2 - a0, ph = a3 - a1;
      float gx = px + pw * dx;
      float gy = py + ph * dy;
      float gw = pw * expf(dw);
      float gh = ph * expf(dh);
      float fw = (float)(*A.iw), fh = (float)(*A.ih);
      float x1 = fminf(fmaxf(gx - gw * 0.5f, 0.0f), fw);
      float y1 = fminf(fmaxf(gy - gh * 0.5f, 0.0f), fh);
      float x2 = fminf(fmaxf(gx + gw * 0.5f, 0.0f), fw);
      float y2 = fminf(fmaxf(gy + gh * 0.5f, 0.0f), fh);
      A.boxes[t] = make_float4(x1, y1, x2, y2);
      if (!((x2 - x1 > 0.0f) && (y2 - y1 > 0.0f))) s = -1.0f;
      A.fkey[t] = ((u64)fmono(s) << 32) | (u32)(~(u32)slot);
    }
  }
  grid.sync();

  // ================= stage S5: per-level stable valid-compaction (blocks 0-9) =================
  if (blk < 10) {
    const int img = blk / 5, lvl = blk % 5;
    const int k = d_kvals[lvl], off = d_segoff[lvl];
    const u64* fk = A.fkey + (size_t)img * M_CAND + off;
    u64* vk = A.vkeys + (size_t)img * M_CAND + off;
    int* cm = A.comp + (size_t)img * M_CAND + off;
    if (tid == 0) s_vb = 0;
    __syncthreads();
    const int lane = tid & 63, wid = tid >> 6;
    const u64 ltm = lane ? (~0ull >> (64 - lane)) : 0ull;
    for (int base = 0; base < k; base += 256) {
      int t = base + tid;
      bool act = t < k;
      u64 key = act ? fk[t] : 0ull;
      bool v = act && (key >> 63);
      u64 bal = __ballot(v);
      int pv = __popcll(bal & ltm);
      if (lane == 0) wvt[wid] = __popcll(bal);
      __syncthreads();
      int voff = 0;
      for (int w2 = 0; w2 < wid; ++w2) voff += wvt[w2];
      int vb = s_vb;
      if (act) {
        int nvb = vb + voff + pv;
        if (v) { vk[nvb] = key; cm[t] = nvb; }
        else   { cm[t] = t - nvb; }
      }
      __syncthreads();
      if (tid == 0) s_vb = vb + wvt[0] + wvt[1] + wvt[2] + wvt[3];
      __syncthreads();
    }
    if (tid == 0) A.vcnt[img * 8 + lvl] = s_vb;
  }
  grid.sync();

  // ================= stage S6: global rank via 5-way merge + scatter (grid-stride) =================
  {
    int t = blk * 256 + tid;
    if (t < 2 * M_CAND) {
      int img = t / M_CAND;
      u64 key = A.fkey[t];
      bool valid = (key >> 63) != 0;
      int lvl = (int)(A.cpos[t] >> 20);
      int vc[5];
      for (int l = 0; l < 5; ++l) vc[l] = A.vcnt[img * 8 + l];
      int r;
      if (valid) {
        r = A.comp[t];
        for (int l = 0; l < 5; ++l) if (l != lvl) {
          const u64* vkp = A.vkeys + (size_t)img * M_CAND + d_segoff[l];
          int lo = 0, hi = vc[l];
          while (lo < hi) { int mid = (lo + hi) >> 1; if (vkp[mid] > key) lo = mid + 1; else hi = mid; }
          r += lo;
        }
      } else {
        int NV = vc[0] + vc[1] + vc[2] + vc[3] + vc[4];
        int ib = 0;
        for (int l = 0; l < lvl; ++l) ib += d_kvals[l] - vc[l];
        r = NV + ib + A.comp[t];
      }
      A.sboxes[(size_t)img * M_CAND + r] = A.boxes[t];
      A.sscore[(size_t)img * M_CAND + r] = fmono_inv((u32)(key >> 32));
    }
  }
  grid.sync();

  // ================= stage S7: suppression bitmask (grid-stride over tasks) =================
  {
    float4* cb = (float4*)SM;           // 64 boxes
    float* ca = (float*)(SM + 1024);    // 64 areas
    const int NTASK = 2 * 28 * 109;     // img x rc x w
    for (int task = blk; task < NTASK; task += 256) {
      int img = task / (28 * 109);
      int r2 = task % (28 * 109);
      int rc = r2 / 109, w = r2 % 109;
      if (rc * 4 > w) continue;         // block-uniform
      const float4* BB = A.sboxes + (size_t)img * M_CAND;
      const int jbase = w << 6;
      if (tid < 64) {
        int j = jbase + tid;
        float4 bj = (j < M_CAND) ? BB[j] : make_float4(0.f, 0.f, 0.f, 0.f);
        cb[tid] = bj;
        ca[tid] = (bj.z - bj.x) * (bj.w - bj.y);
      }
      __syncthreads();
      const int i = rc * 256 + tid;
      if (i < M_CAND) {
        float4 bi = BB[i];
        float areaI = (bi.z - bi.x) * (bi.w - bi.y);
        u64 bits = 0ull;
#pragma unroll 4
        for (int b = 0; b < 64; ++b) {
          float4 bb = cb[b];
          float aj = ca[b];
          float ltx = fmaxf(bi.x, bb.x), lty = fmaxf(bi.y, bb.y);
          float rbx = fminf(bi.z, bb.z), rby = fminf(bi.w, bb.w);
          float ww = fmaxf(rbx - ltx, 0.0f), hh = fmaxf(rby - lty, 0.0f);
          float inter = ww * hh;
          float uni = (areaI + aj) - inter;
          float iou = inter / fmaxf(uni, 1e-9f);
          int jj = jbase + b;
          bits |= ((u64)(iou > 0.7f && jj > i && jj < M_CAND)) << b;
        }
        A.maskp[((size_t)img * M_CAND + i) * MW + w] = bits;
      }
      __syncthreads();
    }
  }
  grid.sync();

  // ================= stage S8: greedy NMS scan (blocks 0,1; wave-specialized) =================
  if (blk < 2) {
    const int img = blk;
    const float4* BB = A.sboxes + (size_t)img * M_CAND;
    const float* SS = A.sscore + (size_t)img * M_CAND;
    const u64* MK = A.maskp + (size_t)img * M_CAND * MW;
    float* out = A.out;
    u64* rem = (u64*)SM;                 // NW words
    int* kl  = (int*)(SM + 1024);        // [2][64] parity kept-row lists
    for (int w0 = tid; w0 < NW; w0 += 256) rem[w0] = 0ull;
    if (tid == 0) { g_tot = 0; g_stop = 0; g_nk[0] = 0; g_nk[1] = 0; }
    __syncthreads();

    u64 myw = 0ull, spw = 0ull; float si = -1.0f;
    if (tid < 64) {
      myw = MK[(size_t)tid * MW];          // diag word 0
      spw = MK[(size_t)tid * MW + 1];      // speculative word 1
      si  = SS[tid];
    }
    int pnk = 0;
    for (int g = 0; g < NW; ++g) {
      const int par = g & 1;
      if (tid < 64) {
        const int i = (g << 6) + tid;
        // prefetch next group's diag+spec+score (independent of resolve)
        u64 nmy = 0ull, nsp = 0ull; float nsi = -1.0f;
        if (g + 1 < NW) {
          int i2 = i + 64;
          if (i2 < M_CAND) {
            nmy = MK[(size_t)i2 * MW + (g + 1)];
            nsi = SS[i2];
            if (g + 2 < NW) nsp = MK[(size_t)i2 * MW + (g + 2)];
          }
        }
        // resolve group g
        u64 validm = __ballot(si > 0.0f);
        u64 rg = rem[g] | ~validm;
        u64 keptm = 0ull, todo = ~rg;
        while (todo) {
          int l = __ffsll(todo) - 1;
          keptm |= 1ull << l;
          rg |= readlane64(myw, l);
          todo = ~rg;
          todo = (l < 63) ? (todo & (~0ull << (l + 1))) : 0ull;
        }
        int ntot = g_tot;
        int nk = __popcll(keptm);
        bool kept = (keptm >> tid) & 1ull;
        int below = __popcll(keptm & ((1ull << tid) - 1ull));
        if (kept) {
          int pos = ntot + below;
          if (pos < 1000) {
            float4 bx = BB[i];
            float* ob = out + ((size_t)img * 1000 + pos) * 4;
            ob[0] = bx.x; ob[1] = bx.y; ob[2] = bx.z; ob[3] = bx.w;
            out[8000 + img * 1000 + pos] = si;
            out[12000 + img * 1000 + pos] = 1.0f;
          }
          kl[par * 64 + below] = i;
        }
        if (keptm) {   // pad kept list to multiple of 16
          int first = (g << 6) + (__ffsll(keptm) - 1);
          int nkp = (nk + 15) & ~15;
          for (int e2 = nk + tid; e2 < nkp; e2 += 64) kl[par * 64 + e2] = first;
        }
        // critical OR for word g+1 via in-register butterfly of speculative words
        if (g + 1 < NW) {
          u64 v = kept ? spw : 0ull;
#pragma unroll
          for (int d = 1; d < 64; d <<= 1) v |= shfl_xor64(v, d);
          if (tid == 0 && v) atomicOr((unsigned long long*)&rem[g + 1], (unsigned long long)v);
        }
        if (tid == 0) {
          g_tot = ntot + nk;
          g_nk[par] = nk;
          g_stop = (ntot + nk >= 1000) || (validm == 0ull);
        }
        myw = nmy; spw = nsp; si = nsi;
      } else {
        // lazy OR: previous group's kept rows -> words >= g+1 (word-outer, 16-batched rows)
        if (pnk > 0) {
          const int lt = tid - 64;
          const int nkp = (pnk + 15) & ~15;
          const int* pk = kl + (par ^ 1) * 64;
          for (int w2 = g + 1 + lt; w2 < NW; w2 += 192) {
            u64 acc = 0ull;
            for (int ki = 0; ki < nkp; ki += 16) {
              u64 v[16];
#pragma unroll
              for (int q = 0; q < 16; ++q) v[q] = MK[(size_t)pk[ki + q] * MW + w2];
#pragma unroll
              for (int q = 0; q < 16; ++q) acc |= v[q];
            }
            if (acc) atomicOr((unsigned long long*)&rem[w2], (unsigned long long)acc);
          }
        }
      }
      __syncthreads();
      if (g_stop) break;
      pnk = g_nk[par];
    }
  }
}

extern "C" void kernel_launch(void* const* d_in, const int* in_sizes, int n_in,
                              void* d_out, int out_size, void* d_ws, size_t ws_size,
                              hipStream_t stream) {
  KArgs A;
  for (int i = 0; i < 5; ++i) {
    A.cls[i] = (const float*)d_in[2 * i];
    A.reg[i] = (const float*)d_in[2 * i + 1];
  }
  A.ih = (const int*)d_in[10];
  A.iw = (const int*)d_in[11];

  char* w = (char*)d_ws;
  A.boxes  = (float4*)(w + OFF_BOX);
  A.sboxes = (float4*)(w + OFF_SBOX);
  A.cscore = (float*)(w + OFF_CS);
  A.cpos   = (u32*)(w + OFF_CP);
  A.sscore = (float*)(w + OFF_SS);
  A.fkey   = (u64*)(w + OFF_KEY);
  A.vkeys  = (u64*)(w + OFF_VK);
  A.vcnt   = (int*)(w + OFF_VC);
  A.comp   = (int*)(w + OFF_CM);
  A.ghist  = (u32*)(w + OFF_GH);
  A.gcnt   = (u32*)(w + OFF_GC);
  A.glist  = (u64*)(w + OFF_GL);
  A.maskp  = (u64*)(w + OFF_MASK);
  A.out    = (float*)d_out;

  void* kp[] = { (void*)&A };
  hipLaunchCooperativeKernel((const void*)k_mega, dim3(256), dim3(256), kp, 0, stream);
}

// Round 9
// 298.258 us; speedup vs baseline: 1.7641x; 1.7641x over previous
//
#include <hip/hip_runtime.h>
#include <math.h>

typedef unsigned long long u64;
typedef unsigned int u32;

#define M_CAND 6960
#define MW 112        // mask row stride in u64 words
#define NW 109

// ws layout (bytes)
#define OFF_BOX   0u          // float4 [2][6960]
#define OFF_SBOX  222720u     // float4 [2][6960]
#define OFF_CS    445440u     // float [2][6960] cand_score
#define OFF_CP    501120u     // u32   [2][6960] cand_pos
#define OFF_SS    556800u     // float [2][6960] sorted scores
#define OFF_KEY   612480u     // u64   [2][6960] full keys
#define OFF_VK    723840u     // u64   [2][6960] valid-compacted keys per level
#define OFF_VC    835200u     // int   [2][8]
#define OFF_CM    835264u     // int   [2][6960] comp indices
#define OFF_MASK  890944u     // u64   [2][6960][112]  (12.47 MB)
// selection scratch ALIASES the mask region (dead before k_mask writes):
#define OFF_GH    OFF_MASK              // u32 [2][16][2048] per-chunk histograms
#define OFF_GC    (OFF_MASK + 262144u)  // u32 [2][18] per-chunk select counts
#define OFF_GL    (OFF_MASK + 262400u)  // u64 [2][18][4096] per-chunk selected lists

__device__ __forceinline__ u32 fmono(float f) {
  u32 u = __float_as_uint(f);
  return (u & 0x80000000u) ? ~u : (u | 0x80000000u);
}
__device__ __forceinline__ float fmono_inv(u32 m) {
  u32 u = (m & 0x80000000u) ? (m & 0x7FFFFFFFu) : ~m;
  return __uint_as_float(u);
}
__device__ __forceinline__ u64 readlane64(u64 v, int l) {
  u32 lo = (u32)__builtin_amdgcn_readlane((int)(u32)v, l);
  u32 hi = (u32)__builtin_amdgcn_readlane((int)(u32)(v >> 32), l);
  return ((u64)hi << 32) | lo;
}
__device__ __forceinline__ u64 shfl_xor64(u64 v, int m) {
  u32 lo = (u32)__shfl_xor((int)(u32)v, m, 64);
  u32 hi = (u32)__shfl_xor((int)(u32)(v >> 32), m, 64);
  return ((u64)hi << 32) | lo;
}

struct Ptrs { const float* cls[5]; const float* reg[5]; const int* ih; const int* iw; };

__device__ const int d_dims[5]    = {128, 64, 32, 16, 8};
__device__ const int d_strides[5] = {8, 16, 32, 64, 128};
__device__ const int d_kvals[5]   = {2000, 2000, 2000, 768, 192};
__device__ const int d_segoff[5]  = {0, 2000, 4000, 6000, 6768};
__device__ const int d_logHW[5]   = {14, 12, 10, 8, 6};
// k_hist: 16 chunk-blocks per image (levels 0-2 only)
__device__ const int d_hlvl[16]   = {0,0,0,0,0,0,0,0,0,0,0,0, 1,1,1, 2};
__device__ const int d_hchk[16]   = {0,1,2,3,4,5,6,7,8,9,10,11, 0,1,2, 0};
__device__ const int d_hbase[3]   = {0, 12, 15};
__device__ const int d_hnum[3]    = {12, 3, 1};
// k_cselect/k_rankL: 18 chunk-blocks per image (all levels)
__device__ const int d_slvl[18]   = {0,0,0,0,0,0,0,0,0,0,0,0, 1,1,1, 2, 3, 4};
__device__ const int d_schk[18]   = {0,1,2,3,4,5,6,7,8,9,10,11, 0,1,2, 0, 0, 0};
__device__ const int d_sbase[5]   = {0, 12, 15, 16, 17};
__device__ const int d_snum[5]    = {12, 3, 1, 1, 1};

__device__ __forceinline__ float sigm(float x) { return 1.0f / (1.0f + expf(-x)); }
__device__ __forceinline__ int binof(float s) {
  int b = (int)(s * 2048.0f);
  return b > 2047 ? 2047 : b;
}

// ---------------- kernel 1a: per-chunk private score histogram ----------------
__global__ __launch_bounds__(256) void k_hist(Ptrs P, u32* ghist) {
  const int bb = blockIdx.x, img = blockIdx.y, tid = threadIdx.x;
  const int lvl = d_hlvl[bb], c0 = d_hchk[bb] << 12;
  const int n = 3 << d_logHW[lvl];
  const float* cls = P.cls[lvl] + (size_t)img * n;
  __shared__ u32 hist[2048];
  for (int b = tid; b < 2048; b += 256) hist[b] = 0;
  __syncthreads();
  const int end = (c0 + 4096 < n) ? c0 + 4096 : n;
  int e = c0 + tid;
  for (; e + 768 < end; e += 1024) {
    float x0 = cls[e], x1 = cls[e + 256], x2 = cls[e + 512], x3 = cls[e + 768];
    atomicAdd(&hist[binof(sigm(x0))], 1u);
    atomicAdd(&hist[binof(sigm(x1))], 1u);
    atomicAdd(&hist[binof(sigm(x2))], 1u);
    atomicAdd(&hist[binof(sigm(x3))], 1u);
  }
  for (; e < end; e += 256) atomicAdd(&hist[binof(sigm(cls[e]))], 1u);
  __syncthreads();
  u32* out = ghist + ((size_t)img * 16 + bb) * 2048;
  for (int b = tid; b < 2048; b += 256) out[b] = hist[b];
}

// ---------------- kernel 1b: fused threshold + chunked select ----------------
__global__ __launch_bounds__(256) void k_cselect(Ptrs P, const u32* ghist, u32* gcnt, u64* glist) {
  const int bb = blockIdx.x, img = blockIdx.y, tid = threadIdx.x;
  const int lvl = d_slvl[bb], c0 = d_schk[bb] << 12;
  const int lhw = d_logHW[lvl];
  const int HW = 1 << lhw, n = 3 * HW;
  const float* cls = P.cls[lvl] + (size_t)img * n;
  const int k = d_kvals[lvl];
  __shared__ u32 shist[2048];
  __shared__ u64 sel[4096];
  __shared__ int s_T, s_cnt;

  if (lvl <= 2) {
    const int hb = d_hbase[lvl], hn = d_hnum[lvl];
    const u32* gh = ghist + ((size_t)img * 16 + hb) * 2048;
    for (int b = tid; b < 2048; b += 256) {
      u32 acc = 0;
      for (int c = 0; c < hn; ++c) acc += gh[(size_t)c * 2048 + b];
      shist[b] = acc;
    }
    __syncthreads();
    if (tid < 64) {
      u32 part = 0;
      for (int j = 0; j < 32; ++j) part += shist[tid * 32 + ((j + tid) & 31)];
      u32 ss = part;
      for (int d = 1; d < 64; d <<= 1) {
        u32 o = __shfl_down(ss, d);
        if (tid + d < 64) ss += o;
      }
      u64 m = __ballot(ss >= (u32)k);
      int SB = 63 - __clzll(m);
      if (tid == SB) {
        u32 acc = ss - part;
        int T = SB * 32;
        for (int b = SB * 32 + 31; b >= SB * 32; --b) {
          acc += shist[b];
          if (acc >= (u32)k) { T = b; break; }
        }
        s_T = T;
      }
    }
  } else if (tid == 0) s_T = 0;
  if (tid == 0) s_cnt = 0;
  __syncthreads();
  const int T = s_T;
  const int end = (c0 + 4096 < n) ? c0 + 4096 : n;
  int e = c0 + tid;
  for (; e + 768 < end; e += 1024) {
    float x0 = cls[e], x1 = cls[e + 256], x2 = cls[e + 512], x3 = cls[e + 768];
    float svals[4] = {sigm(x0), sigm(x1), sigm(x2), sigm(x3)};
    int ee[4] = {e, e + 256, e + 512, e + 768};
    for (int q2 = 0; q2 < 4; ++q2) {
      float s = svals[q2];
      if (binof(s) >= T) {
        int eq = ee[q2];
        int a = eq >> lhw, hw = eq & (HW - 1);
        u32 it = (u32)(hw * 3 + a);
        int p = atomicAdd(&s_cnt, 1);
        sel[p] = ((u64)fmono(s) << 32) | (u32)(~it);
      }
    }
  }
  for (; e < end; e += 256) {
    float s = sigm(cls[e]);
    if (binof(s) >= T) {
      int a = e >> lhw, hw = e & (HW - 1);
      u32 it = (u32)(hw * 3 + a);
      int p = atomicAdd(&s_cnt, 1);
      sel[p] = ((u64)fmono(s) << 32) | (u32)(~it);
    }
  }
  __syncthreads();
  int cnt = s_cnt;
  if (tid == 0) gcnt[img * 18 + bb] = (u32)cnt;
  u64* gl = glist + ((size_t)img * 18 + bb) * 4096;
  for (int p = tid; p < cnt; p += 256) gl[p] = sel[p];
}

// ---------------- kernel 1c: rank within level -> sorted top-k scatter ----------------
__global__ __launch_bounds__(256) void k_rankL(const u32* gcnt, const u64* glist,
                                               float* cand_score, u32* cand_pos) {
  const int lvl = blockIdx.y, img = blockIdx.z, tid = threadIdx.x;
  const int cb = d_sbase[lvl], nc = d_snum[lvl];
  __shared__ __align__(16) u64 sh[4096];
  int cnts[12];
  int tot = 0;
  for (int c = 0; c < nc; ++c) { cnts[c] = (int)gcnt[img * 18 + cb + c]; tot += cnts[c]; }
  if (tot > 4096) tot = 4096;
  const int c0 = blockIdx.x << 8;
  if (c0 >= tot) return;
  int boffs = 0;
  for (int c = 0; c < nc && boffs < tot; ++c) {
    int take = cnts[c];
    int room = tot - boffs;
    if (take > room) take = room;
    const u64* gl = glist + ((size_t)img * 18 + cb + c) * 4096;
    for (int j2 = tid; j2 < take; j2 += 256) sh[boffs + j2] = gl[j2];
    boffs += take;
  }
  if (tid == 0 && (tot & 1)) sh[tot] = 0ull;
  __syncthreads();
  const int p = c0 + tid;
  if (p >= tot) return;
  const u64 mk = sh[p];
  const int cntr = (tot + 1) & ~1;
  int r = 0;
  for (int j = 0; j < cntr; j += 2) {
    ulonglong2 kk = *(const ulonglong2*)&sh[j];
    r += (int)(kk.x > mk) + (int)(kk.y > mk);
  }
  const int k = d_kvals[lvl], off = d_segoff[lvl];
  if (r < k) {
    u32 it = ~(u32)mk;
    cand_score[img * M_CAND + off + r] = fmono_inv((u32)(mk >> 32));
    cand_pos[img * M_CAND + off + r] = ((u32)lvl << 20) | (it & 0xFFFFFu);
  }
}

// ---------------- kernel 2: decode boxes + keys (invalid -> score -1) ----------------
__global__ __launch_bounds__(256) void k_decode(Ptrs P, const float* cand_score, const u32* cand_pos,
                                                float4* boxes, u64* fkey) {
#pragma clang fp contract(off)
  int t = blockIdx.x * 256 + threadIdx.x;
  if (t >= 2 * M_CAND) return;
  int img = t / M_CAND, slot = t - img * M_CAND;
  float s = cand_score[t];
  u32 pc = cand_pos[t];
  int lvl = (int)(pc >> 20), idx = (int)(pc & 0xFFFFFu);
  int W = d_dims[lvl], HW = W * W, stride = d_strides[lvl];
  int a = idx % 3, cell = idx / 3;
  int wx = cell % W, hy = cell / W;
  const float rr[3] = {0.5f, 1.0f, 2.0f};
  float sw = (float)(stride * 8);
  float wsz = sw * sqrtf(1.0f / rr[a]);
  float hsz = sw * sqrtf(rr[a]);
  float ax = (float)(wx * stride), ay = (float)(hy * stride);
  float a0 = ax + (-(wsz * 0.5f));
  float a1 = ay + (-(hsz * 0.5f));
  float a2 = ax + (wsz * 0.5f);
  float a3 = ay + (hsz * 0.5f);
  const float* rg = P.reg[lvl] + ((size_t)img * 12 + (size_t)(a * 4)) * HW + (size_t)hy * W + wx;
  float dx = rg[0], dy = rg[HW], dw = rg[2 * HW], dh = rg[3 * HW];
  const float MR = 4.135166556742356f;
  dw = fminf(fmaxf(dw, -MR), MR);
  dh = fminf(fmaxf(dh, -MR), MR);
  float px = (a0 + a2) * 0.5f, py = (a1 + a3) * 0.5f;
  float pw = a2 - a0, ph = a3 - a1;
  float gx = px + pw * dx;
  float gy = py + ph * dy;
  float gw = pw * expf(dw);
  float gh = ph * expf(dh);
  float fw = (float)(*P.iw), fh = (float)(*P.ih);
  float x1 = fminf(fmaxf(gx - gw * 0.5f, 0.0f), fw);
  float y1 = fminf(fmaxf(gy - gh * 0.5f, 0.0f), fh);
  float x2 = fminf(fmaxf(gx + gw * 0.5f, 0.0f), fw);
  float y2 = fminf(fmaxf(gy + gh * 0.5f, 0.0f), fh);
  boxes[t] = make_float4(x1, y1, x2, y2);
  if (!((x2 - x1 > 0.0f) && (y2 - y1 > 0.0f))) s = -1.0f;
  fkey[t] = ((u64)fmono(s) << 32) | (u32)(~(u32)slot);
}

// ---------------- kernel 3a: per-level stable valid-compaction ----------------
__global__ __launch_bounds__(256) void k_compact(const u64* fkey, u64* vkeys, int* comp, int* vcnt) {
  const int lvl = blockIdx.x, img = blockIdx.y, tid = threadIdx.x;
  const int k = d_kvals[lvl], off = d_segoff[lvl];
  const u64* fk = fkey + (size_t)img * M_CAND + off;
  u64* vk = vkeys + (size_t)img * M_CAND + off;
  int* cm = comp + (size_t)img * M_CAND + off;
  __shared__ int wvt[4];
  __shared__ int s_vb;
  if (tid == 0) s_vb = 0;
  __syncthreads();
  const int lane = tid & 63, wid = tid >> 6;
  const u64 ltm = lane ? (~0ull >> (64 - lane)) : 0ull;
  for (int base = 0; base < k; base += 256) {
    int t = base + tid;
    bool act = t < k;
    u64 key = act ? fk[t] : 0ull;
    bool v = act && (key >> 63);
    u64 bal = __ballot(v);
    int pv = __popcll(bal & ltm);
    if (lane == 0) wvt[wid] = __popcll(bal);
    __syncthreads();
    int voff = 0;
    for (int w2 = 0; w2 < wid; ++w2) voff += wvt[w2];
    int vb = s_vb;
    if (act) {
      int nvb = vb + voff + pv;
      if (v) { vk[nvb] = key; cm[t] = nvb; }
      else   { cm[t] = t - nvb; }
    }
    __syncthreads();
    if (tid == 0) s_vb = vb + wvt[0] + wvt[1] + wvt[2] + wvt[3];
    __syncthreads();
  }
  if (tid == 0) vcnt[img * 8 + lvl] = s_vb;
}

// ---------------- kernel 3b: global rank via 5-way merge + scatter ----------------
__device__ __forceinline__ int count_greater(const u64* vk, int n, u64 key) {
  int lo = 0, hi = n;
  while (lo < hi) {
    int mid = (lo + hi) >> 1;
    if (vk[mid] > key) lo = mid + 1; else hi = mid;
  }
  return lo;
}

__global__ __launch_bounds__(256) void k_rank2(const u64* fkey, const u32* cand_pos,
                                               const int* comp, const int* vcnt,
                                               const u64* vkeys, const float4* boxes,
                                               float4* sboxes, float* sscore) {
  int t = blockIdx.x * 256 + threadIdx.x;
  if (t >= 2 * M_CAND) return;
  int img = t / M_CAND;
  u64 key = fkey[t];
  bool valid = (key >> 63) != 0;
  int lvl = (int)(cand_pos[t] >> 20);
  int vc[5];
  for (int l = 0; l < 5; ++l) vc[l] = vcnt[img * 8 + l];
  int r;
  if (valid) {
    r = comp[t];
    for (int l = 0; l < 5; ++l)
      if (l != lvl) r += count_greater(vkeys + (size_t)img * M_CAND + d_segoff[l], vc[l], key);
  } else {
    int NV = vc[0] + vc[1] + vc[2] + vc[3] + vc[4];
    int ib = 0;
    for (int l = 0; l < lvl; ++l) ib += d_kvals[l] - vc[l];
    r = NV + ib + comp[t];
  }
  sboxes[(size_t)img * M_CAND + r] = boxes[t];
  sscore[(size_t)img * M_CAND + r] = fmono_inv((u32)(key >> 32));
}

// ---------------- kernel 4: suppression bitmask (one word per thread) ----------------
__global__ __launch_bounds__(256) void k_mask(const float4* sboxes, u64* mask) {
#pragma clang fp contract(off)
  const int w = blockIdx.x, rc = blockIdx.y, img = blockIdx.z;
  if (rc * 4 > w) return;
  const int tid = threadIdx.x;
  const float4* BB = sboxes + (size_t)img * M_CAND;
  const int jbase = w << 6;
  __shared__ float4 cb[64];
  __shared__ float ca[64];
  if (tid < 64) {
    int j = jbase + tid;
    float4 bj = (j < M_CAND) ? BB[j] : make_float4(0.f, 0.f, 0.f, 0.f);
    cb[tid] = bj;
    ca[tid] = (bj.z - bj.x) * (bj.w - bj.y);
  }
  __syncthreads();
  const int i = rc * 256 + tid;
  if (i >= M_CAND) return;
  float4 bi = BB[i];
  float areaI = (bi.z - bi.x) * (bi.w - bi.y);
  u64 bits = 0ull;
#pragma unroll 4
  for (int b = 0; b < 64; ++b) {
    float4 bb = cb[b];
    float aj = ca[b];
    float ltx = fmaxf(bi.x, bb.x), lty = fmaxf(bi.y, bb.y);
    float rbx = fminf(bi.z, bb.z), rby = fminf(bi.w, bb.w);
    float ww = fmaxf(rbx - ltx, 0.0f), hh = fmaxf(rby - lty, 0.0f);
    float inter = ww * hh;
    float uni = (areaI + aj) - inter;
    float iou = inter / fmaxf(uni, 1e-9f);
    int jj = jbase + b;
    bits |= ((u64)(iou > 0.7f && jj > i && jj < M_CAND)) << b;
  }
  mask[((size_t)img * M_CAND + i) * MW + w] = bits;
}

// ---------------- kernel 5: wave-specialized greedy NMS scan ----------------
// wave0: resolve group g + critical OR (word g+1 via speculative-word butterfly)
// waves1-3: lazy OR (previous group's kept rows -> words >= g+1; word-outer, 16-row-batched)
__global__ __launch_bounds__(256) void k_scan(const float4* sboxes, const float* sscore,
                                              const u64* mask, float* out) {
  const int img = blockIdx.x, tid = threadIdx.x;
  const float4* BB = sboxes + (size_t)img * M_CAND;
  const float* SS = sscore + (size_t)img * M_CAND;
  const u64* MK = mask + (size_t)img * M_CAND * MW;

  __shared__ u64 rem[NW];
  __shared__ int kl[2][64];     // parity-buffered kept-row lists
  __shared__ int g_tot, g_stop, g_nk[2];

  for (int w0 = tid; w0 < NW; w0 += 256) rem[w0] = 0ull;
  if (tid == 0) { g_tot = 0; g_stop = 0; g_nk[0] = 0; g_nk[1] = 0; }
  __syncthreads();

  u64 myw = 0ull, spw = 0ull; float si = -1.0f;
  if (tid < 64) {
    myw = MK[(size_t)tid * MW];          // diag word 0
    spw = MK[(size_t)tid * MW + 1];      // speculative word 1
    si  = SS[tid];
  }
  int pnk = 0;
  for (int g = 0; g < NW; ++g) {
    const int par = g & 1;
    if (tid < 64) {
      const int i = (g << 6) + tid;
      // prefetch next group's diag+spec+score (independent of resolve)
      u64 nmy = 0ull, nsp = 0ull; float nsi = -1.0f;
      if (g + 1 < NW) {
        int i2 = i + 64;
        if (i2 < M_CAND) {
          nmy = MK[(size_t)i2 * MW + (g + 1)];
          nsi = SS[i2];
          if (g + 2 < NW) nsp = MK[(size_t)i2 * MW + (g + 2)];
        }
      }
      // resolve group g
      u64 validm = __ballot(si > 0.0f);
      u64 rg = rem[g] | ~validm;
      u64 keptm = 0ull, todo = ~rg;
      while (todo) {
        int l = __ffsll(todo) - 1;
        keptm |= 1ull << l;
        rg |= readlane64(myw, l);
        todo = ~rg;
        todo = (l < 63) ? (todo & (~0ull << (l + 1))) : 0ull;
      }
      int ntot = g_tot;
      int nk = __popcll(keptm);
      bool kept = (keptm >> tid) & 1ull;
      int below = __popcll(keptm & ((1ull << tid) - 1ull));
      if (kept) {
        int pos = ntot + below;
        if (pos < 1000) {
          float4 bx = BB[i];
          float* ob = out + ((size_t)img * 1000 + pos) * 4;
          ob[0] = bx.x; ob[1] = bx.y; ob[2] = bx.z; ob[3] = bx.w;
          out[8000 + img * 1000 + pos] = si;
          out[12000 + img * 1000 + pos] = 1.0f;
        }
        kl[par][below] = i;
      }
      if (keptm) {   // pad kept list to multiple of 16
        int first = (g << 6) + (__ffsll(keptm) - 1);
        int nkp = (nk + 15) & ~15;
        for (int e2 = nk + tid; e2 < nkp; e2 += 64) kl[par][e2] = first;
      }
      // critical OR for word g+1 via in-register butterfly of speculative words
      if (g + 1 < NW) {
        u64 v = kept ? spw : 0ull;
#pragma unroll
        for (int d = 1; d < 64; d <<= 1) v |= shfl_xor64(v, d);
        if (tid == 0 && v) atomicOr((unsigned long long*)&rem[g + 1], (unsigned long long)v);
      }
      if (tid == 0) {
        g_tot = ntot + nk;
        g_nk[par] = nk;
        g_stop = (ntot + nk >= 1000) || (validm == 0ull);
      }
      myw = nmy; spw = nsp; si = nsi;
    } else {
      // lazy OR: previous group's kept rows -> words >= g+1 (word-outer, 16-batched rows)
      if (pnk > 0) {
        const int lt = tid - 64;
        const int nkp = (pnk + 15) & ~15;
        const int* pk = kl[par ^ 1];
        for (int w2 = g + 1 + lt; w2 < NW; w2 += 192) {
          u64 acc = 0ull;
          for (int ki = 0; ki < nkp; ki += 16) {
            u64 v[16];
#pragma unroll
            for (int q = 0; q < 16; ++q) v[q] = MK[(size_t)pk[ki + q] * MW + w2];
#pragma unroll
            for (int q = 0; q < 16; ++q) acc |= v[q];
          }
          if (acc) atomicOr((unsigned long long*)&rem[w2], (unsigned long long)acc);
        }
      }
    }
    __syncthreads();
    if (g_stop) break;
    pnk = g_nk[par];
  }

  int total = g_tot;
  int filled = total < 1000 ? total : 1000;
  for (int p = filled + tid; p < 1000; p += 256) {
    float* ob = out + ((size_t)img * 1000 + p) * 4;
    ob[0] = 0.0f; ob[1] = 0.0f; ob[2] = 0.0f; ob[3] = 0.0f;
    out[8000 + img * 1000 + p] = 0.0f;
    out[12000 + img * 1000 + p] = 0.0f;
  }
  for (int p = tid; p < 1000; p += 256) out[10000 + img * 1000 + p] = 0.0f;
}

extern "C" void kernel_launch(void* const* d_in, const int* in_sizes, int n_in,
                              void* d_out, int out_size, void* d_ws, size_t ws_size,
                              hipStream_t stream) {
  Ptrs P;
  for (int i = 0; i < 5; ++i) {
    P.cls[i] = (const float*)d_in[2 * i];
    P.reg[i] = (const float*)d_in[2 * i + 1];
  }
  P.ih = (const int*)d_in[10];
  P.iw = (const int*)d_in[11];

  char* w = (char*)d_ws;
  float4* boxes  = (float4*)(w + OFF_BOX);
  float4* sboxes = (float4*)(w + OFF_SBOX);
  float*  cscore = (float*)(w + OFF_CS);
  u32*    cpos   = (u32*)(w + OFF_CP);
  float*  sscore = (float*)(w + OFF_SS);
  u64*    fkey   = (u64*)(w + OFF_KEY);
  u64*    vkeys  = (u64*)(w + OFF_VK);
  int*    vcnt   = (int*)(w + OFF_VC);
  int*    comp   = (int*)(w + OFF_CM);
  u32*    ghist  = (u32*)(w + OFF_GH);
  u32*    gcnt   = (u32*)(w + OFF_GC);
  u64*    glist  = (u64*)(w + OFF_GL);
  u64*    maskp  = (u64*)(w + OFF_MASK);
  float* out = (float*)d_out;

  hipLaunchKernelGGL(k_hist,    dim3(16, 2),     dim3(256), 0, stream, P, ghist);
  hipLaunchKernelGGL(k_cselect, dim3(18, 2),     dim3(256), 0, stream, P, ghist, gcnt, glist);
  hipLaunchKernelGGL(k_rankL,   dim3(16, 5, 2),  dim3(256), 0, stream, gcnt, glist, cscore, cpos);
  hipLaunchKernelGGL(k_decode,  dim3((2 * M_CAND + 255) / 256), dim3(256), 0, stream, P, cscore, cpos, boxes, fkey);
  hipLaunchKernelGGL(k_compact, dim3(5, 2),      dim3(256), 0, stream, fkey, vkeys, comp, vcnt);
  hipLaunchKernelGGL(k_rank2,   dim3((2 * M_CAND + 255) / 256), dim3(256), 0, stream,
                     fkey, cpos, comp, vcnt, vkeys, boxes, sboxes, sscore);
  hipLaunchKernelGGL(k_mask,    dim3(NW, 28, 2), dim3(256), 0, stream, sboxes, maskp);
  hipLaunchKernelGGL(k_scan,    dim3(2),         dim3(256), 0, stream, sboxes, sscore, maskp, out);
}